// Round 1
// baseline (859.315 us; speedup 1.0000x reference)
//
#include <hip/hip_runtime.h>
#include <math.h>

#define HH    1024
#define WWID  1024
#define WR    513
#define WPAD  520
#define NIMG  96
#define NGRP  65
#define KSEG  17
#define NB    16
#define FEAT  256
#define FIN   144

__device__ __forceinline__ float2 cmul(float2 a, float2 b) {
    return make_float2(a.x * b.x - a.y * b.y, a.x * b.y + a.y * b.x);
}

// bit-exact replication of the reference binning:
// u = k/1024, v = (hf<512 ? hf : hf-1024)/1024  (exact in f32)
// rad = sqrtf(u*u + v*v)  (u*u+v*v exact: (j^2 + i^2) <= 2^19 fits f32 mantissa)
// lowers[l] = (maxr * l) / 16, maxr = sqrtf(0.5f)
__device__ __forceinline__ int radial_bin(int hf, int k) {
    const float maxr = 0.707106781186547524f; // == sqrtf(0.5f) correctly rounded
    float v = (float)(hf < 512 ? hf : hf - 1024) * (1.0f / 1024.0f);
    float u = (float)k * (1.0f / 1024.0f);
    float rad = sqrtf(u * u + v * v);
    int bin = 0;
#pragma unroll
    for (int l = 1; l <= 16; ++l) {
        float lower = (maxr * (float)l) * 0.0625f; // /16 exact
        bin += (rad >= lower) ? 1 : 0;
    }
    return bin;
}

// ---------------- Kernel 1: row FFTs (2 real rows packed per complex FFT) -------------
__global__ __launch_bounds__(256) void k_rowfft(const float* __restrict__ x,
                                                float2* __restrict__ interm,
                                                int img0) {
    __shared__ float2 bufA[1024];
    __shared__ float2 bufB[1024];
    __shared__ float2 tw[512];
    const int t = threadIdx.x;
    const int r = blockIdx.x;   // row pair 0..511
    const int iy = blockIdx.y;  // image within chunk
    const int img = img0 + iy;
    const int h1 = 2 * r, h2 = 2 * r + 1;

    for (int i = t; i < 512; i += 256) {
        float ang = -6.28318530717958647692f * ((float)i * (1.0f / 1024.0f));
        float sn, cs;
        sincosf(ang, &sn, &cs);
        tw[i] = make_float2(cs, sn);
    }

    const float* row1 = x + ((size_t)img * HH + h1) * WWID;
    const float* row2 = x + ((size_t)img * HH + h2) * WWID;
    for (int i = t; i < 1024; i += 256)
        bufA[i] = make_float2(row1[i], row2[i]);
    __syncthreads();

    // Stockham radix-2, autosorting (natural-order output), 10 stages
    float2* src = bufA;
    float2* dst = bufB;
    for (int s = 0; s < 10; ++s) {
        const int m = 1 << s;
#pragma unroll
        for (int it = 0; it < 2; ++it) {
            int p = t + it * 256;          // pair index 0..511
            int jm = p & ~(m - 1);         // j*m
            float2 a = src[p];
            float2 b = src[p + 512];
            float2 w = tw[jm];
            dst[p + jm] = make_float2(a.x + b.x, a.y + b.y);
            float2 d = make_float2(a.x - b.x, a.y - b.y);
            dst[p + jm + m] = cmul(d, w);
        }
        __syncthreads();
        float2* tmp = src; src = dst; dst = tmp;
    }
    // 10 stages (even) -> result back in bufA == src

    // unpack Z = A + iB into rfft(A), rfft(B); store [h][k], k-contiguous
    float2* out1 = interm + ((size_t)iy * HH + h1) * WPAD;
    float2* out2 = interm + ((size_t)iy * HH + h2) * WPAD;
    for (int k = t; k <= 512; k += 256) {
        float2 z = src[k];
        float2 zn = src[(1024 - k) & 1023];
        out1[k] = make_float2(0.5f * (z.x + zn.x), 0.5f * (z.y - zn.y));
        out2[k] = make_float2(0.5f * (z.y + zn.y), 0.5f * (zn.x - z.x));
    }
    if (t < WPAD - WR) { // zero pad columns 513..519
        out1[WR + t] = make_float2(0.f, 0.f);
        out2[WR + t] = make_float2(0.f, 0.f);
    }
}

// ------------- Kernel 2: column FFTs (in-place DIF, bit-reversed) + band stats -------
__global__ __launch_bounds__(256) void k_colfft(const float2* __restrict__ interm,
                                                float* __restrict__ partials,
                                                int img0) {
    __shared__ float2 cls[1024][9]; // [pos][col], padded 8->9 to break bank conflicts
    __shared__ float2 tw[512];
    __shared__ float wred[4][KSEG][3];
    const int t = threadIdx.x;
    const int g = blockIdx.x;   // column group (8 cols)
    const int iy = blockIdx.y;
    const int img = img0 + iy;
    const int kbase = g * 8;

    for (int i = t; i < 512; i += 256) {
        float ang = -6.28318530717958647692f * ((float)i * (1.0f / 1024.0f));
        float sn, cs;
        sincosf(ang, &sn, &cs);
        tw[i] = make_float2(cs, sn);
    }

    const float2* base = interm + (size_t)iy * HH * WPAD + kbase;
    for (int it = 0; it < 32; ++it) {
        int idx = t + it * 256;
        int col = idx & 7;
        int p = idx >> 3;
        cls[p][col] = base[(size_t)p * WPAD + col];
    }
    __syncthreads();

    // in-place DIF radix-2; output at position p is X[bitrev10(p)]
    for (int s = 0; s < 10; ++s) {
        const int len = 512 >> s;
        for (int it = 0; it < 16; ++it) {
            int i = t + it * 256;          // 4096 butterflies (8 cols x 512)
            int col = i & 7;
            int q = i >> 3;
            int j = q & (len - 1);
            int idx0 = ((q >> (9 - s)) << (10 - s)) + j;
            int idx1 = idx0 + len;
            float2 a = cls[idx0][col];
            float2 b = cls[idx1][col];
            cls[idx0][col] = make_float2(a.x + b.x, a.y + b.y);
            float2 d = make_float2(a.x - b.x, a.y - b.y);
            cls[idx1][col] = cmul(d, tw[j << s]);
        }
        __syncthreads();
    }

    // band stats: predicated register accumulators (no runtime indexing -> no scratch)
    float s1[KSEG], s2[KSEG], mx[KSEG];
#pragma unroll
    for (int l = 0; l < KSEG; ++l) { s1[l] = 0.f; s2[l] = 0.f; mx[l] = 0.f; }

    for (int it = 0; it < 32; ++it) {
        int idx = t + it * 256;
        int col = idx & 7;
        int p = idx >> 3;
        int k = kbase + col;
        float2 z = cls[p][col];
        float mag = sqrtf(z.x * z.x + z.y * z.y) * (1.0f / 1024.0f); // ortho norm
        int hf = (int)(__brev((unsigned)p) >> 22);
        int bin = radial_bin(hf, k);
        bool valid = (k < WR);
        float m = valid ? mag : 0.0f;
#pragma unroll
        for (int l = 0; l < KSEG; ++l) {
            float mm = (bin == l) ? m : 0.0f;
            s1[l] += mm;
            s2[l] += mm * m;
            mx[l] = fmaxf(mx[l], mm);
        }
    }

    const int lane = t & 63;
    const int wv = t >> 6;
#pragma unroll
    for (int l = 0; l < KSEG; ++l) {
        float a = s1[l], b = s2[l], c = mx[l];
        for (int off = 32; off > 0; off >>= 1) {
            a += __shfl_xor(a, off);
            b += __shfl_xor(b, off);
            c = fmaxf(c, __shfl_xor(c, off));
        }
        if (lane == 0) { wred[wv][l][0] = a; wred[wv][l][1] = b; wred[wv][l][2] = c; }
    }
    __syncthreads();
    if (t < KSEG) {
        float a = wred[0][t][0] + wred[1][t][0] + wred[2][t][0] + wred[3][t][0];
        float b = wred[0][t][1] + wred[1][t][1] + wred[2][t][1] + wred[3][t][1];
        float c = fmaxf(fmaxf(wred[0][t][2], wred[1][t][2]),
                        fmaxf(wred[2][t][2], wred[3][t][2]));
        float* dstp = partials + ((size_t)img * NGRP + g) * (KSEG * 3) + t * 3;
        dstp[0] = a; dstp[1] = b; dstp[2] = c;
    }
}

// ---------------- counts (data-independent, integer atomics: deterministic) ----------
__global__ __launch_bounds__(256) void k_counts(unsigned* __restrict__ counts) {
    int cnt[KSEG];
#pragma unroll
    for (int l = 0; l < KSEG; ++l) cnt[l] = 0;
    const int total = HH * WR;
    for (int idx = blockIdx.x * 256 + threadIdx.x; idx < total; idx += gridDim.x * 256) {
        int h = idx / WR;
        int k = idx - h * WR;
        int bin = radial_bin(h, k);
#pragma unroll
        for (int l = 0; l < KSEG; ++l) cnt[l] += (bin == l) ? 1 : 0;
    }
    const int lane = threadIdx.x & 63;
#pragma unroll
    for (int l = 0; l < KSEG; ++l) {
        int c = cnt[l];
        for (int off = 32; off > 0; off >>= 1) c += __shfl_xor(c, off);
        if (lane == 0 && c > 0) atomicAdd(&counts[l], (unsigned)c);
    }
}

// ---------------- Kernel 3: finalize stats + MLP + LayerNorm -------------------------
__global__ __launch_bounds__(256) void k_mlp(const float* __restrict__ partials,
                                             const unsigned* __restrict__ counts,
                                             const float* __restrict__ W1,
                                             const float* __restrict__ b1,
                                             const float* __restrict__ W2,
                                             const float* __restrict__ b2,
                                             const float* __restrict__ gamma,
                                             const float* __restrict__ beta,
                                             float* __restrict__ out) {
    __shared__ float feat[FIN];
    __shared__ float h1s[FEAT];
    __shared__ float red[FEAT];
    const int b = blockIdx.x;
    const int t = threadIdx.x;
    if (t < 48) {
        int c = t / 16;
        int bin = t % 16;
        const float* p = partials + ((size_t)(b * 3 + c) * NGRP) * (KSEG * 3) + bin * 3;
        float s1 = 0.f, s2 = 0.f, mxv = 0.f;
        for (int gg = 0; gg < NGRP; ++gg) {
            s1 += p[gg * (KSEG * 3) + 0];
            s2 += p[gg * (KSEG * 3) + 1];
            mxv = fmaxf(mxv, p[gg * (KSEG * 3) + 2]);
        }
        float cntf = (float)counts[bin];
        float denom = cntf + 1e-8f;
        float mean = s1 / denom;
        float var = (s2 - 2.0f * mean * s1 + cntf * mean * mean) / denom;
        var = fmaxf(var, 0.0f);
        float sd = sqrtf(var);
        mxv = fmaxf(mxv, 0.0f);
        // feat layout: (band, stat{mean,max,std}, channel)
        feat[bin * 9 + 0 + c] = mean;
        feat[bin * 9 + 3 + c] = mxv;
        feat[bin * 9 + 6 + c] = sd;
    }
    __syncthreads();

    float acc = b1[t];
    for (int i = 0; i < FIN; ++i) acc += feat[i] * W1[i * FEAT + t];
    acc = (acc >= 0.0f) ? acc : 0.2f * acc; // leaky relu
    h1s[t] = acc;
    __syncthreads();

    float acc2 = b2[t];
    for (int i = 0; i < FEAT; ++i) acc2 += h1s[i] * W2[i * FEAT + t];

    red[t] = acc2;
    __syncthreads();
    for (int off = 128; off > 0; off >>= 1) {
        if (t < off) red[t] += red[t + off];
        __syncthreads();
    }
    float mu = red[0] * (1.0f / 256.0f);
    __syncthreads();
    float dvt = acc2 - mu;
    red[t] = dvt * dvt;
    __syncthreads();
    for (int off = 128; off > 0; off >>= 1) {
        if (t < off) red[t] += red[t + off];
        __syncthreads();
    }
    float va = red[0] * (1.0f / 256.0f);
    out[(size_t)b * FEAT + t] = dvt / sqrtf(va + 1e-5f) * gamma[t] + beta[t];
}

// --------------------------------------------------------------------------------------
extern "C" void kernel_launch(void* const* d_in, const int* in_sizes, int n_in,
                              void* d_out, int out_size, void* d_ws, size_t ws_size,
                              hipStream_t stream) {
    const float* x     = (const float*)d_in[0];
    const float* W1    = (const float*)d_in[1];
    const float* b1    = (const float*)d_in[2];
    const float* W2    = (const float*)d_in[3];
    const float* b2    = (const float*)d_in[4];
    const float* gamma = (const float*)d_in[5];
    const float* beta  = (const float*)d_in[6];
    float* out = (float*)d_out;

    char* ws = (char*)d_ws;
    unsigned* counts = (unsigned*)ws;
    float* partials = (float*)(ws + 256);
    const size_t partialsBytes = (size_t)NIMG * NGRP * KSEG * 3 * sizeof(float);
    const size_t intermOff = (256 + partialsBytes + 255) & ~(size_t)255;
    float2* interm = (float2*)(ws + intermOff);
    const size_t perImg = (size_t)HH * WPAD * sizeof(float2);

    long long avail = (long long)ws_size - (long long)intermOff;
    int chunk = (avail > 0) ? (int)(avail / (long long)perImg) : 0;
    if (chunk > NIMG) chunk = NIMG;
    if (chunk < 1) chunk = 1;

    hipMemsetAsync(counts, 0, KSEG * sizeof(unsigned), stream);
    k_counts<<<dim3(128), dim3(256), 0, stream>>>(counts);

    for (int img0 = 0; img0 < NIMG; img0 += chunk) {
        int n = NIMG - img0;
        if (n > chunk) n = chunk;
        k_rowfft<<<dim3(512, n), dim3(256), 0, stream>>>(x, interm, img0);
        k_colfft<<<dim3(NGRP, n), dim3(256), 0, stream>>>(interm, partials, img0);
    }

    k_mlp<<<dim3(32), dim3(256), 0, stream>>>(partials, counts, W1, b1, W2, b2,
                                              gamma, beta, out);
}

// Round 2
// 842.477 us; speedup vs baseline: 1.0200x; 1.0200x over previous
//
#include <hip/hip_runtime.h>
#include <math.h>

#define HH    1024
#define WWID  1024
#define WR    513
#define WPAD  520
#define NIMG  96
#define NGRP  65
#define KSEG  17
#define NB    16
#define FEAT  256
#define FIN   144

__device__ __forceinline__ float2 cmul(float2 a, float2 b) {
    return make_float2(a.x * b.x - a.y * b.y, a.x * b.y + a.y * b.x);
}

// Bank-spreading swizzle: bijective involution within each 256-element window.
// Pure relabeling of LDS slots -> correctness-neutral, spreads short aligned
// runs (the len<16 DIF stages / bit-reversed reads) across all 32 banks.
__device__ __forceinline__ int IDX(int i) { return i ^ ((i >> 4) & 15); }

// bit-exact replication of the reference binning (see round-0 derivation)
__device__ __forceinline__ int radial_bin(int hf, int k) {
    const float maxr = 0.707106781186547524f;
    float v = (float)(hf < 512 ? hf : hf - 1024) * (1.0f / 1024.0f);
    float u = (float)k * (1.0f / 1024.0f);
    float rad = sqrtf(u * u + v * v);
    int bin = 0;
#pragma unroll
    for (int l = 1; l <= 16; ++l) {
        float lower = (maxr * (float)l) * 0.0625f;
        bin += (rad >= lower) ? 1 : 0;
    }
    return bin;
}

// ---------------- Kernel 1: row FFTs (2 real rows packed per complex FFT) -------------
__global__ __launch_bounds__(256) void k_rowfft(const float* __restrict__ x,
                                                float2* __restrict__ interm,
                                                int img0) {
    __shared__ float2 bufA[1024];
    __shared__ float2 bufB[1024];
    __shared__ float2 tw[512];
    const int t = threadIdx.x;
    const int r = blockIdx.x;   // row pair 0..511
    const int iy = blockIdx.y;  // image within chunk
    const int img = img0 + iy;
    const int h1 = 2 * r, h2 = 2 * r + 1;

    for (int i = t; i < 512; i += 256) {
        float ang = -6.28318530717958647692f * ((float)i * (1.0f / 1024.0f));
        float sn, cs;
        sincosf(ang, &sn, &cs);
        tw[i] = make_float2(cs, sn);
    }

    const float* row1 = x + ((size_t)img * HH + h1) * WWID;
    const float* row2 = x + ((size_t)img * HH + h2) * WWID;
    for (int i = t; i < 1024; i += 256)
        bufA[IDX(i)] = make_float2(row1[i], row2[i]);
    __syncthreads();

    // Stockham radix-2, autosorting (natural-order output), 10 stages
    float2* src = bufA;
    float2* dst = bufB;
    for (int s = 0; s < 10; ++s) {
        const int m = 1 << s;
#pragma unroll
        for (int it = 0; it < 2; ++it) {
            int p = t + it * 256;          // pair index 0..511
            int jm = p & ~(m - 1);         // (p div m)*m
            float2 a = src[IDX(p)];
            float2 b = src[IDX(p + 512)];
            float2 w = tw[jm];
            dst[IDX(p + jm)] = make_float2(a.x + b.x, a.y + b.y);
            float2 d = make_float2(a.x - b.x, a.y - b.y);
            dst[IDX(p + jm + m)] = cmul(d, w);
        }
        __syncthreads();
        float2* tmp = src; src = dst; dst = tmp;
    }
    // 10 stages (even) -> result back in bufA == src

    // unpack Z = A + iB into rfft(A), rfft(B); store [h][k], k-contiguous
    float2* out1 = interm + ((size_t)iy * HH + h1) * WPAD;
    float2* out2 = interm + ((size_t)iy * HH + h2) * WPAD;
    for (int k = t; k <= 512; k += 256) {
        float2 z = src[IDX(k)];
        float2 zn = src[IDX((1024 - k) & 1023)];
        out1[k] = make_float2(0.5f * (z.x + zn.x), 0.5f * (z.y - zn.y));
        out2[k] = make_float2(0.5f * (z.y + zn.y), 0.5f * (zn.x - z.x));
    }
    if (t < WPAD - WR) { // zero pad columns 513..519
        out1[WR + t] = make_float2(0.f, 0.f);
        out2[WR + t] = make_float2(0.f, 0.f);
    }
}

// ------------- Kernel 2: column FFTs (in-place DIF, bit-reversed) + band stats -------
// 512 threads, 8 columns per block, ONE WAVE PER COLUMN, per-column contiguous
// LDS (stride 1028 float2) + IDX bank swizzle.
__global__ __launch_bounds__(512, 4) void k_colfft(const float2* __restrict__ interm,
                                                   float* __restrict__ partials,
                                                   int img0) {
    __shared__ float2 cls[8][1028];
    __shared__ float2 tw[512];
    __shared__ float wred[8][KSEG][3];
    const int t = threadIdx.x;
    const int g = blockIdx.x;   // column group (8 cols)
    const int iy = blockIdx.y;
    const int img = img0 + iy;
    const int kbase = g * 8;

    for (int i = t; i < 512; i += 512) {
        float ang = -6.28318530717958647692f * ((float)i * (1.0f / 1024.0f));
        float sn, cs;
        sincosf(ang, &sn, &cs);
        tw[i] = make_float2(cs, sn);
    }

    // load tile: lanes sweep 8 cols (contiguous 64B global segments)
    const float2* base = interm + (size_t)iy * HH * WPAD + kbase;
    {
        const int col = t & 7;
        const int p0 = t >> 3;
#pragma unroll
        for (int it = 0; it < 16; ++it) {
            int p = p0 + it * 64;
            cls[col][IDX(p)] = base[(size_t)p * WPAD + col];
        }
    }
    __syncthreads();

    // in-place DIF radix-2; output at position p is X[bitrev10(p)]
    const int colw = t >> 6;     // wave-private column
    const int lq   = t & 63;
    for (int s = 0; s < 10; ++s) {
        const int len = 512 >> s;
#pragma unroll
        for (int it = 0; it < 8; ++it) {
            int q = lq + it * 64;          // butterfly index 0..511
            int j = q & (len - 1);
            int idx0 = ((q >> (9 - s)) << (10 - s)) + j;
            int idx1 = idx0 + len;
            float2 a = cls[colw][IDX(idx0)];
            float2 b = cls[colw][IDX(idx1)];
            cls[colw][IDX(idx0)] = make_float2(a.x + b.x, a.y + b.y);
            float2 d = make_float2(a.x - b.x, a.y - b.y);
            cls[colw][IDX(idx1)] = cmul(d, tw[j << s]);
        }
        __syncthreads();
    }

    // band stats: predicated register accumulators
    float s1[KSEG], s2[KSEG], mx[KSEG];
#pragma unroll
    for (int l = 0; l < KSEG; ++l) { s1[l] = 0.f; s2[l] = 0.f; mx[l] = 0.f; }

    const int k = kbase + colw;
    const bool valid = (k < WR);
#pragma unroll
    for (int it = 0; it < 16; ++it) {
        int p = lq + it * 64;
        float2 z = cls[colw][IDX(p)];
        float mag = sqrtf(z.x * z.x + z.y * z.y) * (1.0f / 1024.0f); // ortho norm
        int hf = (int)(__brev((unsigned)p) >> 22);
        int bin = radial_bin(hf, k);
        float m = valid ? mag : 0.0f;
#pragma unroll
        for (int l = 0; l < KSEG; ++l) {
            float mm = (bin == l) ? m : 0.0f;
            s1[l] += mm;
            s2[l] += mm * m;
            mx[l] = fmaxf(mx[l], mm);
        }
    }

    const int lane = t & 63;
    const int wv = t >> 6;
#pragma unroll
    for (int l = 0; l < KSEG; ++l) {
        float a = s1[l], b = s2[l], c = mx[l];
        for (int off = 32; off > 0; off >>= 1) {
            a += __shfl_xor(a, off);
            b += __shfl_xor(b, off);
            c = fmaxf(c, __shfl_xor(c, off));
        }
        if (lane == 0) { wred[wv][l][0] = a; wred[wv][l][1] = b; wred[wv][l][2] = c; }
    }
    __syncthreads();
    if (t < KSEG) {
        float a = 0.f, b = 0.f, c = 0.f;
#pragma unroll
        for (int w = 0; w < 8; ++w) {
            a += wred[w][t][0];
            b += wred[w][t][1];
            c = fmaxf(c, wred[w][t][2]);
        }
        float* dstp = partials + ((size_t)img * NGRP + g) * (KSEG * 3) + t * 3;
        dstp[0] = a; dstp[1] = b; dstp[2] = c;
    }
}

// ---------------- counts (data-independent, integer atomics: deterministic) ----------
__global__ __launch_bounds__(256) void k_counts(unsigned* __restrict__ counts) {
    int cnt[KSEG];
#pragma unroll
    for (int l = 0; l < KSEG; ++l) cnt[l] = 0;
    const int total = HH * WR;
    for (int idx = blockIdx.x * 256 + threadIdx.x; idx < total; idx += gridDim.x * 256) {
        int h = idx / WR;
        int k = idx - h * WR;
        int bin = radial_bin(h, k);
#pragma unroll
        for (int l = 0; l < KSEG; ++l) cnt[l] += (bin == l) ? 1 : 0;
    }
    const int lane = threadIdx.x & 63;
#pragma unroll
    for (int l = 0; l < KSEG; ++l) {
        int c = cnt[l];
        for (int off = 32; off > 0; off >>= 1) c += __shfl_xor(c, off);
        if (lane == 0 && c > 0) atomicAdd(&counts[l], (unsigned)c);
    }
}

// ---------------- Kernel 3: finalize stats + MLP + LayerNorm -------------------------
__global__ __launch_bounds__(256) void k_mlp(const float* __restrict__ partials,
                                             const unsigned* __restrict__ counts,
                                             const float* __restrict__ W1,
                                             const float* __restrict__ b1,
                                             const float* __restrict__ W2,
                                             const float* __restrict__ b2,
                                             const float* __restrict__ gamma,
                                             const float* __restrict__ beta,
                                             float* __restrict__ out) {
    __shared__ float feat[FIN];
    __shared__ float h1s[FEAT];
    __shared__ float red[FEAT];
    const int b = blockIdx.x;
    const int t = threadIdx.x;
    if (t < 48) {
        int c = t / 16;
        int bin = t % 16;
        const float* p = partials + ((size_t)(b * 3 + c) * NGRP) * (KSEG * 3) + bin * 3;
        float s1 = 0.f, s2 = 0.f, mxv = 0.f;
        for (int gg = 0; gg < NGRP; ++gg) {
            s1 += p[gg * (KSEG * 3) + 0];
            s2 += p[gg * (KSEG * 3) + 1];
            mxv = fmaxf(mxv, p[gg * (KSEG * 3) + 2]);
        }
        float cntf = (float)counts[bin];
        float denom = cntf + 1e-8f;
        float mean = s1 / denom;
        float var = (s2 - 2.0f * mean * s1 + cntf * mean * mean) / denom;
        var = fmaxf(var, 0.0f);
        float sd = sqrtf(var);
        mxv = fmaxf(mxv, 0.0f);
        feat[bin * 9 + 0 + c] = mean;
        feat[bin * 9 + 3 + c] = mxv;
        feat[bin * 9 + 6 + c] = sd;
    }
    __syncthreads();

    float acc = b1[t];
    for (int i = 0; i < FIN; ++i) acc += feat[i] * W1[i * FEAT + t];
    acc = (acc >= 0.0f) ? acc : 0.2f * acc; // leaky relu
    h1s[t] = acc;
    __syncthreads();

    float acc2 = b2[t];
    for (int i = 0; i < FEAT; ++i) acc2 += h1s[i] * W2[i * FEAT + t];

    red[t] = acc2;
    __syncthreads();
    for (int off = 128; off > 0; off >>= 1) {
        if (t < off) red[t] += red[t + off];
        __syncthreads();
    }
    float mu = red[0] * (1.0f / 256.0f);
    __syncthreads();
    float dvt = acc2 - mu;
    red[t] = dvt * dvt;
    __syncthreads();
    for (int off = 128; off > 0; off >>= 1) {
        if (t < off) red[t] += red[t + off];
        __syncthreads();
    }
    float va = red[0] * (1.0f / 256.0f);
    out[(size_t)b * FEAT + t] = dvt / sqrtf(va + 1e-5f) * gamma[t] + beta[t];
}

// --------------------------------------------------------------------------------------
extern "C" void kernel_launch(void* const* d_in, const int* in_sizes, int n_in,
                              void* d_out, int out_size, void* d_ws, size_t ws_size,
                              hipStream_t stream) {
    const float* x     = (const float*)d_in[0];
    const float* W1    = (const float*)d_in[1];
    const float* b1    = (const float*)d_in[2];
    const float* W2    = (const float*)d_in[3];
    const float* b2    = (const float*)d_in[4];
    const float* gamma = (const float*)d_in[5];
    const float* beta  = (const float*)d_in[6];
    float* out = (float*)d_out;

    char* ws = (char*)d_ws;
    unsigned* counts = (unsigned*)ws;
    float* partials = (float*)(ws + 256);
    const size_t partialsBytes = (size_t)NIMG * NGRP * KSEG * 3 * sizeof(float);
    const size_t intermOff = (256 + partialsBytes + 255) & ~(size_t)255;
    float2* interm = (float2*)(ws + intermOff);
    const size_t perImg = (size_t)HH * WPAD * sizeof(float2);

    long long avail = (long long)ws_size - (long long)intermOff;
    int chunk = (avail > 0) ? (int)(avail / (long long)perImg) : 0;
    if (chunk > NIMG) chunk = NIMG;
    if (chunk < 1) chunk = 1;

    hipMemsetAsync(counts, 0, KSEG * sizeof(unsigned), stream);
    k_counts<<<dim3(128), dim3(256), 0, stream>>>(counts);

    for (int img0 = 0; img0 < NIMG; img0 += chunk) {
        int n = NIMG - img0;
        if (n > chunk) n = chunk;
        k_rowfft<<<dim3(512, n), dim3(256), 0, stream>>>(x, interm, img0);
        k_colfft<<<dim3(NGRP, n), dim3(512), 0, stream>>>(interm, partials, img0);
    }

    k_mlp<<<dim3(32), dim3(256), 0, stream>>>(partials, counts, W1, b1, W2, b2,
                                              gamma, beta, out);
}

// Round 3
// 664.795 us; speedup vs baseline: 1.2926x; 1.2673x over previous
//
#include <hip/hip_runtime.h>
#include <math.h>

#define HH    1024
#define WWID  1024
#define WR    513
#define WPAD  520
#define NIMG  96
#define NGRP  65
#define KSEG  17
#define NB    16
#define FEAT  256
#define FIN   144

#define PI_F 3.14159265358979323846f

__device__ __forceinline__ float2 cmul(float2 a, float2 b) {
    return make_float2(a.x * b.x - a.y * b.y, a.x * b.y + a.y * b.x);
}

// Bank-spreading swizzle (used by k_rowfft only)
__device__ __forceinline__ int IDX(int i) { return i ^ ((i >> 4) & 15); }

// bit-exact replication of the reference binning
__device__ __forceinline__ int radial_bin(int hf, int k) {
    const float maxr = 0.707106781186547524f;
    float v = (float)(hf < 512 ? hf : hf - 1024) * (1.0f / 1024.0f);
    float u = (float)k * (1.0f / 1024.0f);
    float rad = sqrtf(u * u + v * v);
    int bin = 0;
#pragma unroll
    for (int l = 1; l <= 16; ++l) {
        float lower = (maxr * (float)l) * 0.0625f;
        bin += (rad >= lower) ? 1 : 0;
    }
    return bin;
}

// ---------------- Kernel 1: row FFTs (2 real rows packed per complex FFT) -------------
__global__ __launch_bounds__(256) void k_rowfft(const float* __restrict__ x,
                                                float2* __restrict__ interm,
                                                int img0) {
    __shared__ float2 bufA[1024];
    __shared__ float2 bufB[1024];
    __shared__ float2 tw[512];
    const int t = threadIdx.x;
    const int r = blockIdx.x;
    const int iy = blockIdx.y;
    const int img = img0 + iy;
    const int h1 = 2 * r, h2 = 2 * r + 1;

    for (int i = t; i < 512; i += 256) {
        float ang = -6.28318530717958647692f * ((float)i * (1.0f / 1024.0f));
        float sn, cs;
        sincosf(ang, &sn, &cs);
        tw[i] = make_float2(cs, sn);
    }

    const float* row1 = x + ((size_t)img * HH + h1) * WWID;
    const float* row2 = x + ((size_t)img * HH + h2) * WWID;
    for (int i = t; i < 1024; i += 256)
        bufA[IDX(i)] = make_float2(row1[i], row2[i]);
    __syncthreads();

    float2* src = bufA;
    float2* dst = bufB;
    for (int s = 0; s < 10; ++s) {
        const int m = 1 << s;
#pragma unroll
        for (int it = 0; it < 2; ++it) {
            int p = t + it * 256;
            int jm = p & ~(m - 1);
            float2 a = src[IDX(p)];
            float2 b = src[IDX(p + 512)];
            float2 w = tw[jm];
            dst[IDX(p + jm)] = make_float2(a.x + b.x, a.y + b.y);
            float2 d = make_float2(a.x - b.x, a.y - b.y);
            dst[IDX(p + jm + m)] = cmul(d, w);
        }
        __syncthreads();
        float2* tmp = src; src = dst; dst = tmp;
    }

    float2* out1 = interm + ((size_t)iy * HH + h1) * WPAD;
    float2* out2 = interm + ((size_t)iy * HH + h2) * WPAD;
    for (int k = t; k <= 512; k += 256) {
        float2 z = src[IDX(k)];
        float2 zn = src[IDX((1024 - k) & 1023)];
        out1[k] = make_float2(0.5f * (z.x + zn.x), 0.5f * (z.y - zn.y));
        out2[k] = make_float2(0.5f * (z.y + zn.y), 0.5f * (zn.x - z.x));
    }
    if (t < WPAD - WR) {
        out1[WR + t] = make_float2(0.f, 0.f);
        out2[WR + t] = make_float2(0.f, 0.f);
    }
}

// ------------- Kernel 2: column FFTs — register-resident four-step (16 x 64) ---------
// One column per wave. Lane l holds x[l + 64*j], j=0..15.
// Step A: 16-pt DIT FFT in registers (natural-order output over k2).
// Step B: twiddle W_1024^{l*k2}.
// Step C: 64-pt DIF FFT across lanes via __shfl_xor (bit-reversed lane order).
// Lane p, reg r  <->  X[16*bitrev6(p) + r].
__global__ __launch_bounds__(512) void k_colfft(const float2* __restrict__ interm,
                                                float* __restrict__ partials,
                                                int img0) {
    __shared__ float2 cls[8][1028];          // stride 1028 -> conflict-floor staging
    __shared__ float wsum[8][KSEG][2];       // per-wave s1,s2
    __shared__ unsigned wmax[8][KSEG];       // per-wave max (float bits, mags >= 0)
    const int t = threadIdx.x;
    const int g = blockIdx.x;
    const int iy = blockIdx.y;
    const int img = img0 + iy;
    const int kbase = g * 8;

    for (int i = t; i < 8 * KSEG; i += 512) {
        int w = i / KSEG, bb = i - w * KSEG;
        wsum[w][bb][0] = 0.f; wsum[w][bb][1] = 0.f; wmax[w][bb] = 0u;
    }

    // coalesced global -> LDS staging (8 cols x 1024 rows)
    const float2* base = interm + (size_t)iy * HH * WPAD + kbase;
    {
        const int col = t & 7;
        const int p0 = t >> 3;
#pragma unroll
        for (int it2 = 0; it2 < 16; ++it2) {
            int p = p0 + it2 * 64;
            cls[col][p] = base[(size_t)p * WPAD + col];
        }
    }
    __syncthreads();

    const int wv = t >> 6;       // wave = column
    const int l  = t & 63;       // lane
    const int k  = kbase + wv;

    // ---- load 16 strided elements, bit-reversed register placement (for DIT) ----
    static constexpr int BR4[16] = {0,8,4,12,2,10,6,14,1,9,5,13,3,11,7,15};
    float2 a[16];
#pragma unroll
    for (int j = 0; j < 16; ++j)
        a[BR4[j]] = cls[wv][l + 64 * j];

    // ---- Step A: 16-point DIT FFT in registers ----
    constexpr float TW16C[8] = {1.f, 0.9238795325112867f, 0.7071067811865476f,
                                0.3826834323650898f, 0.f, -0.3826834323650898f,
                                -0.7071067811865476f, -0.9238795325112867f};
    constexpr float TW16S[8] = {0.f, -0.3826834323650898f, -0.7071067811865476f,
                                -0.9238795325112867f, -1.f, -0.9238795325112867f,
                                -0.7071067811865476f, -0.3826834323650898f};
#pragma unroll
    for (int m = 2; m <= 16; m <<= 1) {
        const int half = m >> 1;
        const int tstep = 16 / m;
#pragma unroll
        for (int bse = 0; bse < 16; bse += m) {
#pragma unroll
            for (int jj = 0; jj < 8; ++jj) {
                if (jj < half) {
                    float2 w = make_float2(TW16C[jj * tstep], TW16S[jj * tstep]);
                    float2 tv = cmul(a[bse + half + jj], w);
                    float2 u0 = a[bse + jj];
                    a[bse + jj]        = make_float2(u0.x + tv.x, u0.y + tv.y);
                    a[bse + half + jj] = make_float2(u0.x - tv.x, u0.y - tv.y);
                }
            }
        }
    }

    // ---- Step B: twiddle by W_1024^{l*r} ----
#pragma unroll
    for (int r = 1; r < 16; ++r) {
        float ang = (float)(l * r) * (-6.28318530717958647692f / 1024.0f);
        float sn, cs;
        sincosf(ang, &sn, &cs);
        a[r] = cmul(a[r], make_float2(cs, sn));
    }

    // ---- Step C: 64-point DIF FFT across lanes via shuffles ----
#pragma unroll
    for (int half = 32; half >= 1; half >>= 1) {
        int j = l & (half - 1);
        float ang = (float)j * (-PI_F / (float)half);
        float sn, cs;
        sincosf(ang, &sn, &cs);
        float2 twl = make_float2(cs, sn);
        bool up = (l & half) != 0;
#pragma unroll
        for (int r = 0; r < 16; ++r) {
            float ox = __shfl_xor(a[r].x, half);
            float oy = __shfl_xor(a[r].y, half);
            float2 s = up ? make_float2(ox - a[r].x, oy - a[r].y)
                          : make_float2(a[r].x + ox, a[r].y + oy);
            a[r] = up ? cmul(s, twl) : s;
        }
    }

    // ---- stats: lane's 16 rows are contiguous [16b, 16b+15] -> at most 2 bins ----
    const bool valid = (k < WR);
    const int b = (int)(__brev((unsigned)l) >> 26);
    const int h0 = 16 * b;
    const float u = (float)k * (1.0f / 1024.0f);
    const float uu = u * u;
    const int binF = radial_bin(h0, k);
    const int binL = radial_bin(h0 + 15, k);
    const int bHi = (binF > binL) ? binF : binL;
    const float Lmid = (0.707106781186547524f * (float)bHi) * 0.0625f;

    float sA1 = 0.f, sA2 = 0.f, mA = 0.f;
    float sB1 = 0.f, sB2 = 0.f, mB = 0.f;
#pragma unroll
    for (int r = 0; r < 16; ++r) {
        int h = h0 + r;
        float vf = (float)(h < 512 ? h : h - 1024) * (1.0f / 1024.0f);
        float rad = sqrtf(fmaf(vf, vf, uu));
        float2 z = a[r];
        float mag = sqrtf(fmaf(z.x, z.x, z.y * z.y)) * (1.0f / 1024.0f);
        float m = valid ? mag : 0.0f;
        bool c = (rad >= Lmid);           // same compare as reference (bin == bHi)
        float mAs = c ? m : 0.0f;
        float mBs = c ? 0.0f : m;
        sA1 += mAs; sA2 = fmaf(mAs, m, sA2); mA = fmaxf(mA, mAs);
        sB1 += mBs; sB2 = fmaf(mBs, m, sB2); mB = fmaxf(mB, mBs);
    }

    // per-wave merge (deterministic: within-wave HW order, per-wave buffers)
    atomicAdd(&wsum[wv][bHi][0], sA1);
    atomicAdd(&wsum[wv][bHi][1], sA2);
    atomicMax(&wmax[wv][bHi], __float_as_uint(mA));
    if (bHi > 0) {
        atomicAdd(&wsum[wv][bHi - 1][0], sB1);
        atomicAdd(&wsum[wv][bHi - 1][1], sB2);
        atomicMax(&wmax[wv][bHi - 1], __float_as_uint(mB));
    }
    __syncthreads();

    if (t < KSEG) {
        float aS = 0.f, bS = 0.f, cM = 0.f;
#pragma unroll
        for (int w = 0; w < 8; ++w) {
            aS += wsum[w][t][0];
            bS += wsum[w][t][1];
            cM = fmaxf(cM, __uint_as_float(wmax[w][t]));
        }
        float* dstp = partials + ((size_t)img * NGRP + g) * (KSEG * 3) + t * 3;
        dstp[0] = aS; dstp[1] = bS; dstp[2] = cM;
    }
}

// ---------------- counts (data-independent, integer atomics: deterministic) ----------
__global__ __launch_bounds__(256) void k_counts(unsigned* __restrict__ counts) {
    int cnt[KSEG];
#pragma unroll
    for (int l = 0; l < KSEG; ++l) cnt[l] = 0;
    const int total = HH * WR;
    for (int idx = blockIdx.x * 256 + threadIdx.x; idx < total; idx += gridDim.x * 256) {
        int h = idx / WR;
        int k = idx - h * WR;
        int bin = radial_bin(h, k);
#pragma unroll
        for (int l = 0; l < KSEG; ++l) cnt[l] += (bin == l) ? 1 : 0;
    }
    const int lane = threadIdx.x & 63;
#pragma unroll
    for (int l = 0; l < KSEG; ++l) {
        int c = cnt[l];
        for (int off = 32; off > 0; off >>= 1) c += __shfl_xor(c, off);
        if (lane == 0 && c > 0) atomicAdd(&counts[l], (unsigned)c);
    }
}

// ---------------- Kernel 3: finalize stats + MLP + LayerNorm -------------------------
__global__ __launch_bounds__(256) void k_mlp(const float* __restrict__ partials,
                                             const unsigned* __restrict__ counts,
                                             const float* __restrict__ W1,
                                             const float* __restrict__ b1,
                                             const float* __restrict__ W2,
                                             const float* __restrict__ b2,
                                             const float* __restrict__ gamma,
                                             const float* __restrict__ beta,
                                             float* __restrict__ out) {
    __shared__ float feat[FIN];
    __shared__ float h1s[FEAT];
    __shared__ float red[FEAT];
    const int b = blockIdx.x;
    const int t = threadIdx.x;
    if (t < 48) {
        int c = t / 16;
        int bin = t % 16;
        const float* p = partials + ((size_t)(b * 3 + c) * NGRP) * (KSEG * 3) + bin * 3;
        float s1 = 0.f, s2 = 0.f, mxv = 0.f;
        for (int gg = 0; gg < NGRP; ++gg) {
            s1 += p[gg * (KSEG * 3) + 0];
            s2 += p[gg * (KSEG * 3) + 1];
            mxv = fmaxf(mxv, p[gg * (KSEG * 3) + 2]);
        }
        float cntf = (float)counts[bin];
        float denom = cntf + 1e-8f;
        float mean = s1 / denom;
        float var = (s2 - 2.0f * mean * s1 + cntf * mean * mean) / denom;
        var = fmaxf(var, 0.0f);
        float sd = sqrtf(var);
        mxv = fmaxf(mxv, 0.0f);
        feat[bin * 9 + 0 + c] = mean;
        feat[bin * 9 + 3 + c] = mxv;
        feat[bin * 9 + 6 + c] = sd;
    }
    __syncthreads();

    float acc = b1[t];
    for (int i = 0; i < FIN; ++i) acc += feat[i] * W1[i * FEAT + t];
    acc = (acc >= 0.0f) ? acc : 0.2f * acc;
    h1s[t] = acc;
    __syncthreads();

    float acc2 = b2[t];
    for (int i = 0; i < FEAT; ++i) acc2 += h1s[i] * W2[i * FEAT + t];

    red[t] = acc2;
    __syncthreads();
    for (int off = 128; off > 0; off >>= 1) {
        if (t < off) red[t] += red[t + off];
        __syncthreads();
    }
    float mu = red[0] * (1.0f / 256.0f);
    __syncthreads();
    float dvt = acc2 - mu;
    red[t] = dvt * dvt;
    __syncthreads();
    for (int off = 128; off > 0; off >>= 1) {
        if (t < off) red[t] += red[t + off];
        __syncthreads();
    }
    float va = red[0] * (1.0f / 256.0f);
    out[(size_t)b * FEAT + t] = dvt / sqrtf(va + 1e-5f) * gamma[t] + beta[t];
}

// --------------------------------------------------------------------------------------
extern "C" void kernel_launch(void* const* d_in, const int* in_sizes, int n_in,
                              void* d_out, int out_size, void* d_ws, size_t ws_size,
                              hipStream_t stream) {
    const float* x     = (const float*)d_in[0];
    const float* W1    = (const float*)d_in[1];
    const float* b1    = (const float*)d_in[2];
    const float* W2    = (const float*)d_in[3];
    const float* b2    = (const float*)d_in[4];
    const float* gamma = (const float*)d_in[5];
    const float* beta  = (const float*)d_in[6];
    float* out = (float*)d_out;

    char* ws = (char*)d_ws;
    unsigned* counts = (unsigned*)ws;
    float* partials = (float*)(ws + 256);
    const size_t partialsBytes = (size_t)NIMG * NGRP * KSEG * 3 * sizeof(float);
    const size_t intermOff = (256 + partialsBytes + 255) & ~(size_t)255;
    float2* interm = (float2*)(ws + intermOff);
    const size_t perImg = (size_t)HH * WPAD * sizeof(float2);

    long long avail = (long long)ws_size - (long long)intermOff;
    int chunk = (avail > 0) ? (int)(avail / (long long)perImg) : 0;
    if (chunk > NIMG) chunk = NIMG;
    if (chunk < 1) chunk = 1;

    hipMemsetAsync(counts, 0, KSEG * sizeof(unsigned), stream);
    k_counts<<<dim3(128), dim3(256), 0, stream>>>(counts);

    for (int img0 = 0; img0 < NIMG; img0 += chunk) {
        int n = NIMG - img0;
        if (n > chunk) n = chunk;
        k_rowfft<<<dim3(512, n), dim3(256), 0, stream>>>(x, interm, img0);
        k_colfft<<<dim3(NGRP, n), dim3(512), 0, stream>>>(interm, partials, img0);
    }

    k_mlp<<<dim3(32), dim3(256), 0, stream>>>(partials, counts, W1, b1, W2, b2,
                                              gamma, beta, out);
}

// Round 4
// 514.020 us; speedup vs baseline: 1.6718x; 1.2933x over previous
//
#include <hip/hip_runtime.h>
#include <math.h>

#define HH    1024
#define WWID  1024
#define WR    513
#define NIMG  96
#define NGRP  65
#define KSEG  17
#define FEAT  256
#define FIN   144

__device__ __forceinline__ float2 cmul(float2 a, float2 b) {
    return make_float2(a.x * b.x - a.y * b.y, a.x * b.y + a.y * b.x);
}

// bit-exact replication of the reference binning (verified r1-r3)
__device__ __forceinline__ int radial_bin(int hf, int k) {
    const float maxr = 0.707106781186547524f;
    float v = (float)(hf < 512 ? hf : hf - 1024) * (1.0f / 1024.0f);
    float u = (float)k * (1.0f / 1024.0f);
    float rad = sqrtf(u * u + v * v);
    int bin = 0;
#pragma unroll
    for (int l = 1; l <= 16; ++l) {
        float lower = (maxr * (float)l) * 0.0625f;
        bin += (rad >= lower) ? 1 : 0;
    }
    return bin;
}

// ---- register-resident 1024-pt complex FFT per wave (verified structure, r3) --------
// Input: a[BR4[j]] = x[l + 64j].  Output: lane p, reg r  <->  X[16*bitrev6(p) + r].
// Twiddles: ONE sincosf; Step B via w1^r chain; Step C via tw=-u, u<-u^2.
__device__ __forceinline__ void wave_fft1024(float2 a[16], int l) {
    constexpr float TW16C[8] = {1.f, 0.9238795325112867f, 0.7071067811865476f,
                                0.3826834323650898f, 0.f, -0.3826834323650898f,
                                -0.7071067811865476f, -0.9238795325112867f};
    constexpr float TW16S[8] = {0.f, -0.3826834323650898f, -0.7071067811865476f,
                                -0.9238795325112867f, -1.f, -0.9238795325112867f,
                                -0.7071067811865476f, -0.3826834323650898f};
    // Step A: 16-point DIT in registers
#pragma unroll
    for (int m = 2; m <= 16; m <<= 1) {
        const int half = m >> 1;
        const int tstep = 16 / m;
#pragma unroll
        for (int bse = 0; bse < 16; bse += m) {
#pragma unroll
            for (int jj = 0; jj < 8; ++jj) {
                if (jj < half) {
                    float2 w = make_float2(TW16C[jj * tstep], TW16S[jj * tstep]);
                    float2 tv = cmul(a[bse + half + jj], w);
                    float2 u0 = a[bse + jj];
                    a[bse + jj]        = make_float2(u0.x + tv.x, u0.y + tv.y);
                    a[bse + half + jj] = make_float2(u0.x - tv.x, u0.y - tv.y);
                }
            }
        }
    }
    // Step B: a[r] *= W_1024^{l*r} via chain powers of w1
    float sn, cs;
    sincosf((float)l * (-6.28318530717958647692f / 1024.0f), &sn, &cs);
    float2 w1 = make_float2(cs, sn);
    float2 wr = w1;
    a[1] = cmul(a[1], w1);
#pragma unroll
    for (int r = 2; r < 16; ++r) {
        wr = cmul(wr, w1);
        a[r] = cmul(a[r], wr);
    }
    // Step C: 64-point DIF across lanes; stage `half` twiddle for up-lanes is -u,
    // u = e^{-2*pi*i*l/(2*half)}  (starts at w1^16, squared each stage)
    float2 u = cmul(wr, w1); // w1^16
#pragma unroll
    for (int half = 32; half >= 1; half >>= 1) {
        float2 tw = make_float2(-u.x, -u.y);
        bool up = (l & half) != 0;
#pragma unroll
        for (int r = 0; r < 16; ++r) {
            float ox = __shfl_xor(a[r].x, half);
            float oy = __shfl_xor(a[r].y, half);
            float2 s = up ? make_float2(ox - a[r].x, oy - a[r].y)
                          : make_float2(a[r].x + ox, a[r].y + oy);
            a[r] = up ? cmul(s, tw) : s;
        }
        if (half > 1) u = cmul(u, u);
    }
}

static __device__ __constant__ int BR4[16] = {0,8,4,12,2,10,6,14,1,9,5,13,3,11,7,15};

// ---------------- Kernel 1: row FFTs, register-resident; writes k-major interm -------
// Block: 512 thr = 8 waves; wave w does rows (h0+2w, h0+2w+1) packed as one complex FFT.
// Unpack partner Z[1024-k]: lane p^63, reg 16-r (r>=1); r=0 via general shfl.
// Transpose through XOR-swizzled LDS tile -> coalesced [k][h] writes.
__global__ __launch_bounds__(512) void k_rowfft(const float* __restrict__ x,
                                                float2* __restrict__ interm,
                                                int img0) {
    __shared__ float2 tile[WR][17]; // [k][col], stride 17 breaks sweep conflicts
    const int t = threadIdx.x;
    const int w = t >> 6;
    const int l = t & 63;
    const int blk = blockIdx.x;           // 16-row group, 0..63
    const int iy = blockIdx.y;
    const int img = img0 + iy;
    const int h0 = blk * 16;
    const int h1 = h0 + 2 * w, h2 = h1 + 1;

    const float* r1 = x + ((size_t)img * HH + h1) * WWID;
    const float* r2 = x + ((size_t)img * HH + h2) * WWID;
    float2 a[16];
#pragma unroll
    for (int j = 0; j < 16; ++j) {
        int i = l + 64 * j;
        a[BR4[j]] = make_float2(r1[i], r2[i]);
    }

    wave_fft1024(a, l);

    const int b = (int)(__brev((unsigned)l) >> 26);
#pragma unroll
    for (int r = 0; r < 16; ++r) {
        float2 znr;
        if (r == 0) {
            int cblk = (64 - b) & 63;
            int q = (int)(__brev((unsigned)cblk) >> 26);
            znr.x = __shfl(a[0].x, q);
            znr.y = __shfl(a[0].y, q);
        } else {
            znr.x = __shfl_xor(a[16 - r].x, 63);
            znr.y = __shfl_xor(a[16 - r].y, 63);
        }
        int k = 16 * b + r;
        if (k <= 512) {
            float2 A = make_float2(0.5f * (a[r].x + znr.x), 0.5f * (a[r].y - znr.y));
            float2 B = make_float2(0.5f * (a[r].y + znr.y), 0.5f * (znr.x - a[r].x));
            int cc = b & 15;
            tile[k][(2 * w) ^ cc]     = A;
            tile[k][(2 * w + 1) ^ cc] = B;
        }
    }
    __syncthreads();

    // coalesced write-out: [k][h0..h0+15]
    float2* gout = interm + (size_t)iy * WR * HH + h0;
    for (int idx = t; idx < WR * 16; idx += 512) {
        int k = idx >> 4;
        int hh = idx & 15;
        gout[(size_t)k * HH + hh] = tile[k][hh ^ ((k >> 4) & 15)];
    }
}

// ------------- Kernel 2: column FFTs, register-resident, zero staging ---------------
__global__ __launch_bounds__(512) void k_colfft(const float2* __restrict__ interm,
                                                float* __restrict__ partials,
                                                int img0) {
    __shared__ float wsum[8][KSEG][2];
    __shared__ unsigned wmax[8][KSEG];
    const int t = threadIdx.x;
    const int g = blockIdx.x;
    const int iy = blockIdx.y;
    const int img = img0 + iy;
    const int wv = t >> 6;
    const int l = t & 63;
    const int k = g * 8 + wv;

    for (int i = t; i < 8 * KSEG; i += 512) {
        int w = i / KSEG, bb = i - w * KSEG;
        wsum[w][bb][0] = 0.f; wsum[w][bb][1] = 0.f; wmax[w][bb] = 0u;
    }
    __syncthreads();

    if (k <= 512) {   // wave-uniform branch
        const float2* gcol = interm + (size_t)iy * WR * HH + (size_t)k * HH;
        float2 a[16];
#pragma unroll
        for (int j = 0; j < 16; ++j)
            a[BR4[j]] = gcol[l + 64 * j];

        wave_fft1024(a, l);

        // stats: lane's 16 rows contiguous [16b, 16b+15] -> at most 2 bins (verified r3)
        const int b = (int)(__brev((unsigned)l) >> 26);
        const int h0 = 16 * b;
        const float u = (float)k * (1.0f / 1024.0f);
        const float uu = u * u;
        const int binF = radial_bin(h0, k);
        const int binL = radial_bin(h0 + 15, k);
        const int bHi = (binF > binL) ? binF : binL;
        const float Lmid = (0.707106781186547524f * (float)bHi) * 0.0625f;

        float sA1 = 0.f, sA2 = 0.f, mA = 0.f;
        float sB1 = 0.f, sB2 = 0.f, mB = 0.f;
#pragma unroll
        for (int r = 0; r < 16; ++r) {
            int h = h0 + r;
            float vf = (float)(h < 512 ? h : h - 1024) * (1.0f / 1024.0f);
            float rad = sqrtf(fmaf(vf, vf, uu));
            float2 z = a[r];
            float m = sqrtf(fmaf(z.x, z.x, z.y * z.y)) * (1.0f / 1024.0f);
            bool c = (rad >= Lmid);
            float mAs = c ? m : 0.0f;
            float mBs = c ? 0.0f : m;
            sA1 += mAs; sA2 = fmaf(mAs, m, sA2); mA = fmaxf(mA, mAs);
            sB1 += mBs; sB2 = fmaf(mBs, m, sB2); mB = fmaxf(mB, mBs);
        }

        atomicAdd(&wsum[wv][bHi][0], sA1);
        atomicAdd(&wsum[wv][bHi][1], sA2);
        atomicMax(&wmax[wv][bHi], __float_as_uint(mA));
        if (bHi > 0) {
            atomicAdd(&wsum[wv][bHi - 1][0], sB1);
            atomicAdd(&wsum[wv][bHi - 1][1], sB2);
            atomicMax(&wmax[wv][bHi - 1], __float_as_uint(mB));
        }
    }
    __syncthreads();

    if (t < KSEG) {
        float aS = 0.f, bS = 0.f, cM = 0.f;
#pragma unroll
        for (int w = 0; w < 8; ++w) {
            aS += wsum[w][t][0];
            bS += wsum[w][t][1];
            cM = fmaxf(cM, __uint_as_float(wmax[w][t]));
        }
        float* dstp = partials + ((size_t)img * NGRP + g) * (KSEG * 3) + t * 3;
        dstp[0] = aS; dstp[1] = bS; dstp[2] = cM;
    }
}

// ---------------- counts (data-independent, integer atomics: deterministic) ----------
__global__ __launch_bounds__(256) void k_counts(unsigned* __restrict__ counts) {
    int cnt[KSEG];
#pragma unroll
    for (int l = 0; l < KSEG; ++l) cnt[l] = 0;
    const int total = HH * WR;
    for (int idx = blockIdx.x * 256 + threadIdx.x; idx < total; idx += gridDim.x * 256) {
        int h = idx / WR;
        int k = idx - h * WR;
        int bin = radial_bin(h, k);
#pragma unroll
        for (int l = 0; l < KSEG; ++l) cnt[l] += (bin == l) ? 1 : 0;
    }
    const int lane = threadIdx.x & 63;
#pragma unroll
    for (int l = 0; l < KSEG; ++l) {
        int c = cnt[l];
        for (int off = 32; off > 0; off >>= 1) c += __shfl_xor(c, off);
        if (lane == 0 && c > 0) atomicAdd(&counts[l], (unsigned)c);
    }
}

// ---------------- Kernel 3: finalize stats + MLP + LayerNorm -------------------------
__global__ __launch_bounds__(256) void k_mlp(const float* __restrict__ partials,
                                             const unsigned* __restrict__ counts,
                                             const float* __restrict__ W1,
                                             const float* __restrict__ b1,
                                             const float* __restrict__ W2,
                                             const float* __restrict__ b2,
                                             const float* __restrict__ gamma,
                                             const float* __restrict__ beta,
                                             float* __restrict__ out) {
    __shared__ float feat[FIN];
    __shared__ float h1s[FEAT];
    __shared__ float red[FEAT];
    const int b = blockIdx.x;
    const int t = threadIdx.x;
    if (t < 48) {
        int c = t / 16;
        int bin = t % 16;
        const float* p = partials + ((size_t)(b * 3 + c) * NGRP) * (KSEG * 3) + bin * 3;
        float s1 = 0.f, s2 = 0.f, mxv = 0.f;
        for (int gg = 0; gg < NGRP; ++gg) {
            s1 += p[gg * (KSEG * 3) + 0];
            s2 += p[gg * (KSEG * 3) + 1];
            mxv = fmaxf(mxv, p[gg * (KSEG * 3) + 2]);
        }
        float cntf = (float)counts[bin];
        float denom = cntf + 1e-8f;
        float mean = s1 / denom;
        float var = (s2 - 2.0f * mean * s1 + cntf * mean * mean) / denom;
        var = fmaxf(var, 0.0f);
        float sd = sqrtf(var);
        mxv = fmaxf(mxv, 0.0f);
        feat[bin * 9 + 0 + c] = mean;
        feat[bin * 9 + 3 + c] = mxv;
        feat[bin * 9 + 6 + c] = sd;
    }
    __syncthreads();

    float acc = b1[t];
    for (int i = 0; i < FIN; ++i) acc += feat[i] * W1[i * FEAT + t];
    acc = (acc >= 0.0f) ? acc : 0.2f * acc;
    h1s[t] = acc;
    __syncthreads();

    float acc2 = b2[t];
    for (int i = 0; i < FEAT; ++i) acc2 += h1s[i] * W2[i * FEAT + t];

    red[t] = acc2;
    __syncthreads();
    for (int off = 128; off > 0; off >>= 1) {
        if (t < off) red[t] += red[t + off];
        __syncthreads();
    }
    float mu = red[0] * (1.0f / 256.0f);
    __syncthreads();
    float dvt = acc2 - mu;
    red[t] = dvt * dvt;
    __syncthreads();
    for (int off = 128; off > 0; off >>= 1) {
        if (t < off) red[t] += red[t + off];
        __syncthreads();
    }
    float va = red[0] * (1.0f / 256.0f);
    out[(size_t)b * FEAT + t] = dvt / sqrtf(va + 1e-5f) * gamma[t] + beta[t];
}

// --------------------------------------------------------------------------------------
extern "C" void kernel_launch(void* const* d_in, const int* in_sizes, int n_in,
                              void* d_out, int out_size, void* d_ws, size_t ws_size,
                              hipStream_t stream) {
    const float* x     = (const float*)d_in[0];
    const float* W1    = (const float*)d_in[1];
    const float* b1    = (const float*)d_in[2];
    const float* W2    = (const float*)d_in[3];
    const float* b2    = (const float*)d_in[4];
    const float* gamma = (const float*)d_in[5];
    const float* beta  = (const float*)d_in[6];
    float* out = (float*)d_out;

    char* ws = (char*)d_ws;
    unsigned* counts = (unsigned*)ws;
    float* partials = (float*)(ws + 256);
    const size_t partialsBytes = (size_t)NIMG * NGRP * KSEG * 3 * sizeof(float);
    const size_t intermOff = (256 + partialsBytes + 255) & ~(size_t)255;
    float2* interm = (float2*)(ws + intermOff);
    const size_t perImg = (size_t)WR * HH * sizeof(float2);

    long long avail = (long long)ws_size - (long long)intermOff;
    int chunk = (avail > 0) ? (int)(avail / (long long)perImg) : 0;
    if (chunk > NIMG) chunk = NIMG;
    if (chunk < 1) chunk = 1;

    hipMemsetAsync(counts, 0, KSEG * sizeof(unsigned), stream);
    k_counts<<<dim3(128), dim3(256), 0, stream>>>(counts);

    for (int img0 = 0; img0 < NIMG; img0 += chunk) {
        int n = NIMG - img0;
        if (n > chunk) n = chunk;
        k_rowfft<<<dim3(64, n), dim3(512), 0, stream>>>(x, interm, img0);
        k_colfft<<<dim3(NGRP, n), dim3(512), 0, stream>>>(interm, partials, img0);
    }

    k_mlp<<<dim3(32), dim3(256), 0, stream>>>(partials, counts, W1, b1, W2, b2,
                                              gamma, beta, out);
}

// Round 5
// 507.865 us; speedup vs baseline: 1.6920x; 1.0121x over previous
//
#include <hip/hip_runtime.h>
#include <hip/hip_fp16.h>
#include <math.h>

#define HH    1024
#define WWID  1024
#define WR    513
#define NIMG  96
#define NGRP  65
#define KSEG  17
#define FEAT  256
#define FIN   144

__device__ __forceinline__ float2 cmul(float2 a, float2 b) {
    return make_float2(a.x * b.x - a.y * b.y, a.x * b.y + a.y * b.x);
}

// bit-exact replication of the reference binning (verified r1-r4)
__device__ __forceinline__ int radial_bin(int hf, int k) {
    const float maxr = 0.707106781186547524f;
    float v = (float)(hf < 512 ? hf : hf - 1024) * (1.0f / 1024.0f);
    float u = (float)k * (1.0f / 1024.0f);
    float rad = sqrtf(u * u + v * v);
    int bin = 0;
#pragma unroll
    for (int l = 1; l <= 16; ++l) {
        float lower = (maxr * (float)l) * 0.0625f;
        bin += (rad >= lower) ? 1 : 0;
    }
    return bin;
}

// ---- register-resident 1024-pt complex FFT per wave (verified r3/r4) ----------------
// Input: a[BR4[j]] = x[l + 64j].  Output: lane p, reg r  <->  X[16*bitrev6(p) + r].
__device__ __forceinline__ void wave_fft1024(float2 a[16], int l) {
    constexpr float TW16C[8] = {1.f, 0.9238795325112867f, 0.7071067811865476f,
                                0.3826834323650898f, 0.f, -0.3826834323650898f,
                                -0.7071067811865476f, -0.9238795325112867f};
    constexpr float TW16S[8] = {0.f, -0.3826834323650898f, -0.7071067811865476f,
                                -0.9238795325112867f, -1.f, -0.9238795325112867f,
                                -0.7071067811865476f, -0.3826834323650898f};
#pragma unroll
    for (int m = 2; m <= 16; m <<= 1) {
        const int half = m >> 1;
        const int tstep = 16 / m;
#pragma unroll
        for (int bse = 0; bse < 16; bse += m) {
#pragma unroll
            for (int jj = 0; jj < 8; ++jj) {
                if (jj < half) {
                    float2 w = make_float2(TW16C[jj * tstep], TW16S[jj * tstep]);
                    float2 tv = cmul(a[bse + half + jj], w);
                    float2 u0 = a[bse + jj];
                    a[bse + jj]        = make_float2(u0.x + tv.x, u0.y + tv.y);
                    a[bse + half + jj] = make_float2(u0.x - tv.x, u0.y - tv.y);
                }
            }
        }
    }
    float sn, cs;
    sincosf((float)l * (-6.28318530717958647692f / 1024.0f), &sn, &cs);
    float2 w1 = make_float2(cs, sn);
    float2 wr = w1;
    a[1] = cmul(a[1], w1);
#pragma unroll
    for (int r = 2; r < 16; ++r) {
        wr = cmul(wr, w1);
        a[r] = cmul(a[r], wr);
    }
    float2 u = cmul(wr, w1); // w1^16
#pragma unroll
    for (int half = 32; half >= 1; half >>= 1) {
        float2 tw = make_float2(-u.x, -u.y);
        bool up = (l & half) != 0;
#pragma unroll
        for (int r = 0; r < 16; ++r) {
            float ox = __shfl_xor(a[r].x, half);
            float oy = __shfl_xor(a[r].y, half);
            float2 s = up ? make_float2(ox - a[r].x, oy - a[r].y)
                          : make_float2(a[r].x + ox, a[r].y + oy);
            a[r] = up ? cmul(s, tw) : s;
        }
        if (half > 1) u = cmul(u, u);
    }
}

static __device__ __constant__ int BR4[16] = {0,8,4,12,2,10,6,14,1,9,5,13,3,11,7,15};

// ---------------- Kernel 1: row FFTs, register-resident; writes k-major fp16 interm --
__global__ __launch_bounds__(512) void k_rowfft(const float* __restrict__ x,
                                                __half2* __restrict__ interm,
                                                int img0) {
    __shared__ __half2 tile[WR][17]; // [k][col], stride 17 + XOR swizzle on col
    const int t = threadIdx.x;
    const int w = t >> 6;
    const int l = t & 63;
    const int blk = blockIdx.x;           // 16-row group, 0..63
    const int iy = blockIdx.y;
    const int img = img0 + iy;
    const int h0 = blk * 16;
    const int h1 = h0 + 2 * w, h2 = h1 + 1;

    const float* r1 = x + ((size_t)img * HH + h1) * WWID;
    const float* r2 = x + ((size_t)img * HH + h2) * WWID;
    float2 a[16];
#pragma unroll
    for (int j = 0; j < 16; ++j) {
        int i = l + 64 * j;
        a[BR4[j]] = make_float2(r1[i], r2[i]);
    }

    wave_fft1024(a, l);

    const int b = (int)(__brev((unsigned)l) >> 26);
#pragma unroll
    for (int r = 0; r < 16; ++r) {
        float2 znr;
        if (r == 0) {
            int cblk = (64 - b) & 63;
            int q = (int)(__brev((unsigned)cblk) >> 26);
            znr.x = __shfl(a[0].x, q);
            znr.y = __shfl(a[0].y, q);
        } else {
            znr.x = __shfl_xor(a[16 - r].x, 63);
            znr.y = __shfl_xor(a[16 - r].y, 63);
        }
        int k = 16 * b + r;
        if (k <= 512) {
            int cc = b & 15;
            tile[k][(2 * w) ^ cc] =
                __floats2half2_rn(0.5f * (a[r].x + znr.x), 0.5f * (a[r].y - znr.y));
            tile[k][(2 * w + 1) ^ cc] =
                __floats2half2_rn(0.5f * (a[r].y + znr.y), 0.5f * (znr.x - a[r].x));
        }
    }
    __syncthreads();

    // coalesced write-out: [k][h0..h0+15]
    __half2* gout = interm + (size_t)iy * WR * HH + h0;
    for (int idx = t; idx < WR * 16; idx += 512) {
        int k = idx >> 4;
        int hh = idx & 15;
        gout[(size_t)k * HH + hh] = tile[k][hh ^ ((k >> 4) & 15)];
    }
}

// ------------- Kernel 2: column FFTs, register-resident, zero staging ---------------
__global__ __launch_bounds__(512) void k_colfft(const __half2* __restrict__ interm,
                                                float* __restrict__ partials,
                                                int img0) {
    __shared__ float wsum[8][KSEG][2];
    __shared__ unsigned wmax[8][KSEG];
    const int t = threadIdx.x;
    const int g = blockIdx.x;
    const int iy = blockIdx.y;
    const int img = img0 + iy;
    const int wv = t >> 6;
    const int l = t & 63;
    const int k = g * 8 + wv;

    for (int i = t; i < 8 * KSEG; i += 512) {
        int w = i / KSEG, bb = i - w * KSEG;
        wsum[w][bb][0] = 0.f; wsum[w][bb][1] = 0.f; wmax[w][bb] = 0u;
    }
    __syncthreads();

    if (k <= 512) {   // wave-uniform branch
        const __half2* gcol = interm + (size_t)iy * WR * HH + (size_t)k * HH;
        float2 a[16];
#pragma unroll
        for (int j = 0; j < 16; ++j) {
            float2 z = __half22float2(gcol[l + 64 * j]);
            a[BR4[j]] = z;
        }

        wave_fft1024(a, l);

        // stats: lane's 16 rows contiguous [16b, 16b+15] -> at most 2 bins (verified r3)
        const int b = (int)(__brev((unsigned)l) >> 26);
        const int h0 = 16 * b;
        const float u = (float)k * (1.0f / 1024.0f);
        const float uu = u * u;
        const int binF = radial_bin(h0, k);
        const int binL = radial_bin(h0 + 15, k);
        const int bHi = (binF > binL) ? binF : binL;
        const float Lmid = (0.707106781186547524f * (float)bHi) * 0.0625f;

        float sA1 = 0.f, sA2 = 0.f, mA = 0.f;
        float sB1 = 0.f, sB2 = 0.f, mB = 0.f;
#pragma unroll
        for (int r = 0; r < 16; ++r) {
            int h = h0 + r;
            float vf = (float)(h < 512 ? h : h - 1024) * (1.0f / 1024.0f);
            float rad = sqrtf(fmaf(vf, vf, uu));
            float2 z = a[r];
            float m = sqrtf(fmaf(z.x, z.x, z.y * z.y)) * (1.0f / 1024.0f);
            bool c = (rad >= Lmid);
            float mAs = c ? m : 0.0f;
            float mBs = c ? 0.0f : m;
            sA1 += mAs; sA2 = fmaf(mAs, m, sA2); mA = fmaxf(mA, mAs);
            sB1 += mBs; sB2 = fmaf(mBs, m, sB2); mB = fmaxf(mB, mBs);
        }

        atomicAdd(&wsum[wv][bHi][0], sA1);
        atomicAdd(&wsum[wv][bHi][1], sA2);
        atomicMax(&wmax[wv][bHi], __float_as_uint(mA));
        if (bHi > 0) {
            atomicAdd(&wsum[wv][bHi - 1][0], sB1);
            atomicAdd(&wsum[wv][bHi - 1][1], sB2);
            atomicMax(&wmax[wv][bHi - 1], __float_as_uint(mB));
        }
    }
    __syncthreads();

    if (t < KSEG) {
        float aS = 0.f, bS = 0.f, cM = 0.f;
#pragma unroll
        for (int w = 0; w < 8; ++w) {
            aS += wsum[w][t][0];
            bS += wsum[w][t][1];
            cM = fmaxf(cM, __uint_as_float(wmax[w][t]));
        }
        float* dstp = partials + ((size_t)img * NGRP + g) * (KSEG * 3) + t * 3;
        dstp[0] = aS; dstp[1] = bS; dstp[2] = cM;
    }
}

// ---------------- counts (data-independent, integer atomics: deterministic) ----------
__global__ __launch_bounds__(256) void k_counts(unsigned* __restrict__ counts) {
    int cnt[KSEG];
#pragma unroll
    for (int l = 0; l < KSEG; ++l) cnt[l] = 0;
    const int total = HH * WR;
    for (int idx = blockIdx.x * 256 + threadIdx.x; idx < total; idx += gridDim.x * 256) {
        int h = idx / WR;
        int k = idx - h * WR;
        int bin = radial_bin(h, k);
#pragma unroll
        for (int l = 0; l < KSEG; ++l) cnt[l] += (bin == l) ? 1 : 0;
    }
    const int lane = threadIdx.x & 63;
#pragma unroll
    for (int l = 0; l < KSEG; ++l) {
        int c = cnt[l];
        for (int off = 32; off > 0; off >>= 1) c += __shfl_xor(c, off);
        if (lane == 0 && c > 0) atomicAdd(&counts[l], (unsigned)c);
    }
}

// ---------------- Kernel 3: finalize stats + MLP + LayerNorm -------------------------
__global__ __launch_bounds__(256) void k_mlp(const float* __restrict__ partials,
                                             const unsigned* __restrict__ counts,
                                             const float* __restrict__ W1,
                                             const float* __restrict__ b1,
                                             const float* __restrict__ W2,
                                             const float* __restrict__ b2,
                                             const float* __restrict__ gamma,
                                             const float* __restrict__ beta,
                                             float* __restrict__ out) {
    __shared__ float feat[FIN];
    __shared__ float h1s[FEAT];
    __shared__ float red[FEAT];
    const int b = blockIdx.x;
    const int t = threadIdx.x;
    if (t < 48) {
        int c = t / 16;
        int bin = t % 16;
        const float* p = partials + ((size_t)(b * 3 + c) * NGRP) * (KSEG * 3) + bin * 3;
        float s1 = 0.f, s2 = 0.f, mxv = 0.f;
        for (int gg = 0; gg < NGRP; ++gg) {
            s1 += p[gg * (KSEG * 3) + 0];
            s2 += p[gg * (KSEG * 3) + 1];
            mxv = fmaxf(mxv, p[gg * (KSEG * 3) + 2]);
        }
        float cntf = (float)counts[bin];
        float denom = cntf + 1e-8f;
        float mean = s1 / denom;
        float var = (s2 - 2.0f * mean * s1 + cntf * mean * mean) / denom;
        var = fmaxf(var, 0.0f);
        float sd = sqrtf(var);
        mxv = fmaxf(mxv, 0.0f);
        feat[bin * 9 + 0 + c] = mean;
        feat[bin * 9 + 3 + c] = mxv;
        feat[bin * 9 + 6 + c] = sd;
    }
    __syncthreads();

    float acc = b1[t];
    for (int i = 0; i < FIN; ++i) acc += feat[i] * W1[i * FEAT + t];
    acc = (acc >= 0.0f) ? acc : 0.2f * acc;
    h1s[t] = acc;
    __syncthreads();

    float acc2 = b2[t];
    for (int i = 0; i < FEAT; ++i) acc2 += h1s[i] * W2[i * FEAT + t];

    red[t] = acc2;
    __syncthreads();
    for (int off = 128; off > 0; off >>= 1) {
        if (t < off) red[t] += red[t + off];
        __syncthreads();
    }
    float mu = red[0] * (1.0f / 256.0f);
    __syncthreads();
    float dvt = acc2 - mu;
    red[t] = dvt * dvt;
    __syncthreads();
    for (int off = 128; off > 0; off >>= 1) {
        if (t < off) red[t] += red[t + off];
        __syncthreads();
    }
    float va = red[0] * (1.0f / 256.0f);
    out[(size_t)b * FEAT + t] = dvt / sqrtf(va + 1e-5f) * gamma[t] + beta[t];
}

// --------------------------------------------------------------------------------------
extern "C" void kernel_launch(void* const* d_in, const int* in_sizes, int n_in,
                              void* d_out, int out_size, void* d_ws, size_t ws_size,
                              hipStream_t stream) {
    const float* x     = (const float*)d_in[0];
    const float* W1    = (const float*)d_in[1];
    const float* b1    = (const float*)d_in[2];
    const float* W2    = (const float*)d_in[3];
    const float* b2    = (const float*)d_in[4];
    const float* gamma = (const float*)d_in[5];
    const float* beta  = (const float*)d_in[6];
    float* out = (float*)d_out;

    char* ws = (char*)d_ws;
    unsigned* counts = (unsigned*)ws;
    float* partials = (float*)(ws + 256);
    const size_t partialsBytes = (size_t)NIMG * NGRP * KSEG * 3 * sizeof(float);
    const size_t intermOff = (256 + partialsBytes + 255) & ~(size_t)255;
    __half2* interm = (__half2*)(ws + intermOff);
    const size_t perImg = (size_t)WR * HH * sizeof(__half2);

    long long avail = (long long)ws_size - (long long)intermOff;
    int chunk = (avail > 0) ? (int)(avail / (long long)perImg) : 0;
    if (chunk > NIMG) chunk = NIMG;
    if (chunk < 1) chunk = 1;

    hipMemsetAsync(counts, 0, KSEG * sizeof(unsigned), stream);
    k_counts<<<dim3(128), dim3(256), 0, stream>>>(counts);

    for (int img0 = 0; img0 < NIMG; img0 += chunk) {
        int n = NIMG - img0;
        if (n > chunk) n = chunk;
        k_rowfft<<<dim3(64, n), dim3(512), 0, stream>>>(x, interm, img0);
        k_colfft<<<dim3(NGRP, n), dim3(512), 0, stream>>>(interm, partials, img0);
    }

    k_mlp<<<dim3(32), dim3(256), 0, stream>>>(partials, counts, W1, b1, W2, b2,
                                              gamma, beta, out);
}